// Round 1
// baseline (840.277 us; speedup 1.0000x reference)
//
#include <hip/hip_runtime.h>

// Problem constants (fixed by reference setup_inputs)
#define BATCH 4
#define SEQ   4096
#define DIM   2048
#define TD    256                 // threads per block = dims per block
#define LCH   32                  // s-steps per chunk, held in registers
#define CHUNKS (SEQ / LCH)        // 128
#define NGD   (DIM / TD)          // 8 dim-groups
#define NG    (BATCH * NGD)       // 32 chain-groups
#define NBLOCKS (NG * CHUNKS)     // 4096 blocks

// ---- agent-scope (device-coherent) atomic helpers: routed through the
// coherent point, safe across non-coherent per-XCD L2s ----
__device__ __forceinline__ float agent_load_f(const float* p) {
    return __hip_atomic_load(p, __ATOMIC_RELAXED, __HIP_MEMORY_SCOPE_AGENT);
}
__device__ __forceinline__ void agent_store_f(float* p, float v) {
    __hip_atomic_store(p, v, __ATOMIC_RELAXED, __HIP_MEMORY_SCOPE_AGENT);
}

// Decoupled-lookback single-pass scan.
// status[slot]: 0 = empty, 1 = aggregate ready, 2 = inclusive prefix ready
__global__ __launch_bounds__(TD, 1) void scan_lookback_kernel(
    const float* __restrict__ a, const float* __restrict__ b,
    const float* __restrict__ h0, float* __restrict__ out,
    int* __restrict__ ticket, int* __restrict__ status,
    float* __restrict__ aggA, float* __restrict__ aggB,
    float* __restrict__ pref)
{
    __shared__ int s_vid;
    __shared__ int s_st;
    const int tid = threadIdx.x;

    // Ticket: guarantees chunk c is assigned only after all chunks < c (per the
    // vid -> (c,g) mapping below) have been assigned to started blocks, so
    // lookback predecessors are always running-or-done regardless of HW
    // dispatch order. Publishing an aggregate never waits -> no deadlock.
    if (tid == 0) s_vid = atomicAdd(ticket, 1);
    __syncthreads();
    const int vid = s_vid;
    const int c = vid / NG;          // chunk index along s (fills 0,1,2,... last)
    const int g = vid % NG;          // chain-group
    const int batch = g / NGD;
    const int dim = (g % NGD) * TD + tid;

    // 32-bit indexing: max element index 33.5M < 2^31
    const unsigned base = (unsigned)(batch * SEQ + c * LCH) * DIM + dim;
    const float* pa = a + base;
    const float* pb = b + base;

    // Load chunk into registers (coalesced: lanes = consecutive dims)
    float ra[LCH], rb[LCH];
#pragma unroll
    for (int t = 0; t < LCH; ++t) {
        ra[t] = pa[(unsigned)t * DIM];
        rb[t] = pb[(unsigned)t * DIM];
    }

    // In-place local scan: ra[t] -> prod_{0..t} a, rb[t] -> scan from state 0
#pragma unroll
    for (int t = 1; t < LCH; ++t) {
        rb[t] = fmaf(ra[t], rb[t - 1], rb[t]);
        ra[t] = ra[t] * ra[t - 1];
    }

    const int slot = g * CHUNKS + c;
    float h_in;

    if (c == 0) {
        // Initial state folds in h0; we can publish an inclusive prefix at once.
        h_in = h0[batch * DIM + dim];
        const float hend = fmaf(ra[LCH - 1], h_in, rb[LCH - 1]);
        agent_store_f(&pref[(unsigned)slot * TD + tid], hend);
        __syncthreads();   // all value stores drained (barrier waits vmcnt(0))
        if (tid == 0)
            __hip_atomic_store(&status[slot], 2, __ATOMIC_RELEASE, __HIP_MEMORY_SCOPE_AGENT);
    } else {
        // 1) publish our aggregate immediately (never blocks)
        agent_store_f(&aggA[(unsigned)slot * TD + tid], ra[LCH - 1]);
        agent_store_f(&aggB[(unsigned)slot * TD + tid], rb[LCH - 1]);
        __syncthreads();
        if (tid == 0)
            __hip_atomic_store(&status[slot], 1, __ATOMIC_RELEASE, __HIP_MEMORY_SCOPE_AGENT);

        // 2) lookback: walk p = c-1, c-2, ... combining aggregates until a prefix
        float A_run = 1.0f, B_run = 0.0f;   // segment (p+1 .. c-1), identity at start
        int p = c - 1;
        for (;;) {
            const int pslot = g * CHUNKS + p;
            if (tid == 0) {
                int st;
                do {
                    st = __hip_atomic_load(&status[pslot], __ATOMIC_ACQUIRE, __HIP_MEMORY_SCOPE_AGENT);
                    if (st == 0) __builtin_amdgcn_s_sleep(2);
                } while (st == 0);
                s_st = st;
            }
            __syncthreads();
            const int st = s_st;
            __syncthreads();   // everyone consumed s_st before next poll overwrites
            if (st == 2) {
                const float hp = agent_load_f(&pref[(unsigned)pslot * TD + tid]);
                h_in = fmaf(A_run, hp, B_run);
                break;
            } else {
                const float Ap = agent_load_f(&aggA[(unsigned)pslot * TD + tid]);
                const float Bp = agent_load_f(&aggB[(unsigned)pslot * TD + tid]);
                B_run = fmaf(A_run, Bp, B_run);
                A_run = A_run * Ap;
                --p;
            }
        }

        // 3) publish our inclusive prefix ASAP to unblock successors
        const float hend = fmaf(ra[LCH - 1], h_in, rb[LCH - 1]);
        agent_store_f(&pref[(unsigned)slot * TD + tid], hend);
        __syncthreads();
        if (tid == 0)
            __hip_atomic_store(&status[slot], 2, __ATOMIC_RELEASE, __HIP_MEMORY_SCOPE_AGENT);
    }

    // 4) apply carry and store (coalesced)
    float* po = out + base;
#pragma unroll
    for (int t = 0; t < LCH; ++t) {
        po[(unsigned)t * DIM] = fmaf(ra[t], h_in, rb[t]);
    }
}

// Safety-net fallback if workspace is too small: one thread per chain.
__global__ void scan_naive_kernel(
    const float* __restrict__ a, const float* __restrict__ b,
    const float* __restrict__ h0, float* __restrict__ out)
{
    const int chain = blockIdx.x * blockDim.x + threadIdx.x;  // [0, BATCH*DIM)
    if (chain >= BATCH * DIM) return;
    const int batch = chain / DIM;
    const int dim = chain % DIM;
    float h = h0[batch * DIM + dim];
    unsigned idx = (unsigned)(batch * SEQ) * DIM + dim;
    for (int s = 0; s < SEQ; ++s, idx += DIM) {
        h = fmaf(a[idx], h, b[idx]);
        out[idx] = h;
    }
}

extern "C" void kernel_launch(void* const* d_in, const int* in_sizes, int n_in,
                              void* d_out, int out_size, void* d_ws, size_t ws_size,
                              hipStream_t stream) {
    const float* a  = (const float*)d_in[0];
    const float* b  = (const float*)d_in[1];
    const float* h0 = (const float*)d_in[2];
    float* out = (float*)d_out;

    const size_t vals_per_arr = (size_t)NBLOCKS * TD;             // 1M floats = 4 MB
    const size_t need = 65536 + 3 * vals_per_arr * sizeof(float); // ~12.6 MB

    if (ws_size >= need) {
        // ws layout: [ticket @0][status @256 .. 16640][pad][aggA @64K][aggB][pref]
        hipMemsetAsync(d_ws, 0, 32768, stream);  // zero ticket + status (re-poisoned each launch)
        int* ticket = (int*)d_ws;
        int* status = (int*)((char*)d_ws + 256);
        float* aggA = (float*)((char*)d_ws + 65536);
        float* aggB = aggA + vals_per_arr;
        float* pref = aggB + vals_per_arr;
        scan_lookback_kernel<<<dim3(NBLOCKS), dim3(TD), 0, stream>>>(
            a, b, h0, out, ticket, status, aggA, aggB, pref);
    } else {
        scan_naive_kernel<<<dim3((BATCH * DIM + 255) / 256), dim3(256), 0, stream>>>(
            a, b, h0, out);
    }
}

// Round 2
// 373.711 us; speedup vs baseline: 2.2485x; 2.2485x over previous
//
#include <hip/hip_runtime.h>

// Problem constants (fixed by reference setup_inputs)
#define BATCH 4
#define SEQ   4096
#define DIM   2048
#define NC    128               // number of s-chunks
#define LSEG  (SEQ / NC)        // 32 s-steps per chunk
#define D4    (DIM / 4)         // 512 float4 per (batch, s) row
#define GQ    2                 // 256 threads * 4 dims = 1024 dims -> 2 groups per row
#define NBLK  (BATCH * GQ * NC) // 1024 blocks for k1/k3
#define NCHAIN (BATCH * DIM)    // 8192 independent chains

// ---------------- Kernel 1: per-segment aggregates (A, B) ----------------
// Segment operator: appending element (a_t, b_t): (A,B) -> (a_t*A, a_t*B + b_t)
__global__ __launch_bounds__(256) void k1_aggregate(
    const float4* __restrict__ a4, const float4* __restrict__ b4,
    float4* __restrict__ aggA4, float4* __restrict__ aggB4)
{
    const int tid = threadIdx.x;
    const int bx = blockIdx.x;
    const int c     = bx & (NC - 1);
    const int r     = bx >> 7;          // NC = 128
    const int batch = r >> 1;           // GQ = 2
    const int gq    = r & 1;
    const int d4    = gq * 256 + tid;   // float4 index within the D dimension

    unsigned base = (unsigned)(batch * SEQ + c * LSEG) * D4 + d4;

    float4 A = make_float4(1.f, 1.f, 1.f, 1.f);
    float4 B = make_float4(0.f, 0.f, 0.f, 0.f);
#pragma unroll 8
    for (int t = 0; t < LSEG; ++t) {
        const float4 av = a4[base + (unsigned)t * D4];
        const float4 bv = b4[base + (unsigned)t * D4];
        B.x = fmaf(av.x, B.x, bv.x);  A.x *= av.x;
        B.y = fmaf(av.y, B.y, bv.y);  A.y *= av.y;
        B.z = fmaf(av.z, B.z, bv.z);  A.z *= av.z;
        B.w = fmaf(av.w, B.w, bv.w);  A.w *= av.w;
    }
    // agg layout (float units): idx = c*8192 + batch*2048 + dim  -> float4 units:
    const unsigned aidx = (unsigned)c * (NCHAIN / 4) + batch * (DIM / 4) + d4;
    aggA4[aidx] = A;
    aggB4[aidx] = B;
}

// ---------------- Kernel 2: scan aggregates along c per chain ----------------
// pref[c][chain] = state entering chunk c (h after chunks 0..c-1, seeded with h0)
__global__ __launch_bounds__(256) void k2_scan_agg(
    const float* __restrict__ aggA, const float* __restrict__ aggB,
    const float* __restrict__ h0, float* __restrict__ pref)
{
    const int ch = blockIdx.x * 256 + threadIdx.x;  // [0, NCHAIN)
    float h = h0[ch];
#pragma unroll 8
    for (int c = 0; c < NC; ++c) {
        const unsigned idx = (unsigned)c * NCHAIN + ch;
        pref[idx] = h;
        h = fmaf(aggA[idx], h, aggB[idx]);
    }
}

// ---------------- Kernel 3: re-read, apply incoming state, write out ----------------
__global__ __launch_bounds__(256) void k3_apply(
    const float4* __restrict__ a4, const float4* __restrict__ b4,
    const float4* __restrict__ pref4, float4* __restrict__ out4)
{
    const int tid = threadIdx.x;
    const int bx = blockIdx.x;
    const int c     = bx & (NC - 1);
    const int r     = bx >> 7;
    const int batch = r >> 1;
    const int gq    = r & 1;
    const int d4    = gq * 256 + tid;

    unsigned base = (unsigned)(batch * SEQ + c * LSEG) * D4 + d4;
    const unsigned aidx = (unsigned)c * (NCHAIN / 4) + batch * (DIM / 4) + d4;

    float4 h = pref4[aidx];
#pragma unroll 8
    for (int t = 0; t < LSEG; ++t) {
        const float4 av = a4[base + (unsigned)t * D4];
        const float4 bv = b4[base + (unsigned)t * D4];
        h.x = fmaf(av.x, h.x, bv.x);
        h.y = fmaf(av.y, h.y, bv.y);
        h.z = fmaf(av.z, h.z, bv.z);
        h.w = fmaf(av.w, h.w, bv.w);
        out4[base + (unsigned)t * D4] = h;
    }
}

// Safety-net fallback if workspace is too small: one thread per chain.
__global__ void scan_naive_kernel(
    const float* __restrict__ a, const float* __restrict__ b,
    const float* __restrict__ h0, float* __restrict__ out)
{
    const int chain = blockIdx.x * blockDim.x + threadIdx.x;
    if (chain >= NCHAIN) return;
    const int batch = chain / DIM;
    const int dim = chain % DIM;
    float h = h0[batch * DIM + dim];
    unsigned idx = (unsigned)(batch * SEQ) * DIM + dim;
    for (int s = 0; s < SEQ; ++s, idx += DIM) {
        h = fmaf(a[idx], h, b[idx]);
        out[idx] = h;
    }
}

extern "C" void kernel_launch(void* const* d_in, const int* in_sizes, int n_in,
                              void* d_out, int out_size, void* d_ws, size_t ws_size,
                              hipStream_t stream) {
    const float* a  = (const float*)d_in[0];
    const float* b  = (const float*)d_in[1];
    const float* h0 = (const float*)d_in[2];
    float* out = (float*)d_out;

    const size_t seg_vals = (size_t)NC * NCHAIN;            // 1M floats = 4 MB
    const size_t need = 3 * seg_vals * sizeof(float);       // 12 MB

    if (ws_size >= need) {
        float* aggA = (float*)d_ws;
        float* aggB = aggA + seg_vals;
        float* pref = aggB + seg_vals;

        k1_aggregate<<<dim3(NBLK), dim3(256), 0, stream>>>(
            (const float4*)a, (const float4*)b, (float4*)aggA, (float4*)aggB);
        k2_scan_agg<<<dim3(NCHAIN / 256), dim3(256), 0, stream>>>(
            aggA, aggB, h0, pref);
        k3_apply<<<dim3(NBLK), dim3(256), 0, stream>>>(
            (const float4*)a, (const float4*)b, (const float4*)pref, (float4*)out);
    } else {
        scan_naive_kernel<<<dim3((NCHAIN + 255) / 256), dim3(256), 0, stream>>>(
            a, b, h0, out);
    }
}